// Round 1
// baseline (1307.223 us; speedup 1.0000x reference)
//
#include <hip/hip_runtime.h>
#include <math.h>

// ---------------------------------------------------------------------------
// node_update_layer — fp32 baseline for MI355X (gfx950)
//
// Stages:
//  K1: per-(b,d) top-2 over K of uk  + mean_uc = sum_k uk*e_rc      -> ws
//  K3: mean_uk[b,k,d] = (1/S_k) sum_l e[b,l,k] rl[b,l,d]            -> ws
//  K4: mean_rl[b,l,d] = (1/T_l) sum_k e[b,l,k] uk[b,k,d]            -> ws
//  K2: uc MLP -> uc_update                                          -> out
//  K5<0>: fu MLP on concat(uk, loo_max, mean_uk) -> uk_update       -> out
//  K5<1>: f  MLP on concat(rl, mean_rl)          -> rl_update       -> out
//  K7: scores = eu MLP on |uc_update - uk_update|                   -> ws
//  K8: softmax over K                                               -> out
// ---------------------------------------------------------------------------

namespace {
constexpr int nB = 256, nK = 512, nL = 512, nD = 64;
constexpr int NH = 256;   // hidden = 2*CH
constexpr int NC = 128;   // CH
constexpr int OC = 192;   // CH + D

constexpr size_t OUT_UK  = 0;
constexpr size_t OUT_UC  = (size_t)nB * nK * OC;          // 25165824
constexpr size_t OUT_RL  = OUT_UC + (size_t)nB * OC;      // 25214976
constexpr size_t OUT_ERC = OUT_RL + (size_t)nB * nL * OC; // 50380800

constexpr size_t WS_MAX1 = 0;
constexpr size_t WS_MAX2 = WS_MAX1 + (size_t)nB * nD;
constexpr size_t WS_MUC  = WS_MAX2 + (size_t)nB * nD;
constexpr size_t WS_MUK  = WS_MUC + (size_t)nB * nD;
constexpr size_t WS_MRL  = WS_MUK + (size_t)nB * nK * nD;
constexpr size_t WS_SC   = WS_MRL + (size_t)nB * nL * nD;
// total ws = 16,957,440 floats = 67.8 MB
}  // namespace

// --------------------------- K1: top2 + mean_uc ----------------------------
__global__ __launch_bounds__(256) void k1_topk_meanuc(
    const float* __restrict__ uk, const float* __restrict__ e_rc,
    float* __restrict__ ws) {
  const int b = blockIdx.x;
  const int d = threadIdx.x & 63;
  const int g = threadIdx.x >> 6;
  const float* ukb = uk + (size_t)b * nK * nD;
  const float* erb = e_rc + (size_t)b * nK;
  float m1 = -INFINITY, m2 = -INFINITY, s = 0.f;
  for (int k = g; k < nK; k += 4) {
    float v = ukb[(size_t)k * nD + d];
    s = fmaf(v, erb[k], s);
    if (v > m1) { m2 = m1; m1 = v; }
    else if (v > m2) { m2 = v; }
  }
  __shared__ float sm1[4][64], sm2[4][64], ssm[4][64];
  sm1[g][d] = m1; sm2[g][d] = m2; ssm[g][d] = s;
  __syncthreads();
  if (threadIdx.x < 64) {
    float a1 = sm1[0][d], a2 = sm2[0][d], acc = ssm[0][d];
    #pragma unroll
    for (int q = 1; q < 4; ++q) {
      float b1 = sm1[q][d], b2 = sm2[q][d];
      float n1 = fmaxf(a1, b1);
      float n2 = fmaxf(fminf(a1, b1), (a1 >= b1) ? a2 : b2);
      a1 = n1; a2 = n2;
      acc += ssm[q][d];
    }
    ws[WS_MAX1 + (size_t)b * nD + d] = a1;
    ws[WS_MAX2 + (size_t)b * nD + d] = a2;
    ws[WS_MUC  + (size_t)b * nD + d] = acc;
  }
}

// --------------------------- K2: uc MLP ------------------------------------
__global__ __launch_bounds__(256) void k2_uc_mlp(
    const float* __restrict__ uc, const float* __restrict__ ws,
    const float* __restrict__ w1, const float* __restrict__ b1,
    const float* __restrict__ w2, const float* __restrict__ b2,
    float* __restrict__ out) {
  const int b = blockIdx.x;
  const int t = threadIdx.x;
  __shared__ float x[128], h[256];
  if (t < 64) x[t] = ws[WS_MUC + (size_t)b * nD + t];
  else if (t < 128) x[t] = uc[(size_t)b * nD + (t - 64)];
  __syncthreads();
  float acc = b1[t];
  for (int i = 0; i < 128; ++i) acc = fmaf(x[i], w1[(size_t)i * NH + t], acc);
  h[t] = fmaxf(acc, 0.f);
  __syncthreads();
  if (t < 128) {
    float a2 = b2[t];
    for (int j = 0; j < 256; ++j) a2 = fmaf(h[j], w2[(size_t)j * NC + t], a2);
    out[OUT_UC + (size_t)b * OC + t] = a2;
  } else if (t < 192) {
    out[OUT_UC + (size_t)b * OC + t] = uc[(size_t)b * nD + (t - 128)];
  }
}

// --------------------------- K3: mean_uk GEMM ------------------------------
// block = (ktile of 128 k, b); reduce over L in chunks of 32.
__global__ __launch_bounds__(256) void k3_mean_uk(
    const float* __restrict__ e, const float* __restrict__ rl,
    float* __restrict__ ws) {
  const int kt = blockIdx.x;   // 0..3
  const int b  = blockIdx.y;
  __shared__ float et[32 * 132];  // [l][k] stride 132
  __shared__ float rt[32 * 68];   // [l][d] stride 68
  __shared__ float ssh[128];
  const int tid = threadIdx.x;
  const int kq = tid >> 4, dq = tid & 15;
  const int k0 = kq * 8, d0 = dq * 4;
  float acc[8][4];
  #pragma unroll
  for (int i = 0; i < 8; ++i)
    #pragma unroll
    for (int j = 0; j < 4; ++j) acc[i][j] = 0.f;
  float s8[8] = {0, 0, 0, 0, 0, 0, 0, 0};
  if (tid < 128) ssh[tid] = 0.f;

  const float* eb = e + (size_t)b * nL * nK + (size_t)kt * 128;
  const float* rb = rl + (size_t)b * nL * nD;
  const int li = tid >> 3;
  const int jseg = (tid & 7) * 16;
  const int dseg = (tid & 7) * 8;

  for (int lt = 0; lt < 16; ++lt) {
    const float* er = eb + (size_t)(lt * 32 + li) * nK;
    #pragma unroll
    for (int q = 0; q < 4; ++q) {
      float4 v = *(const float4*)(er + jseg + 4 * q);
      *(float4*)&et[li * 132 + jseg + 4 * q] = v;
    }
    const float* rr = rb + (size_t)(lt * 32 + li) * nD;
    #pragma unroll
    for (int q = 0; q < 2; ++q) {
      float4 v = *(const float4*)(rr + dseg + 4 * q);
      *(float4*)&rt[li * 68 + dseg + 4 * q] = v;
    }
    __syncthreads();
    #pragma unroll 4
    for (int l = 0; l < 32; ++l) {
      float4 e0 = *(const float4*)&et[l * 132 + k0];
      float4 e1 = *(const float4*)&et[l * 132 + k0 + 4];
      float4 rv = *(const float4*)&rt[l * 68 + d0];
      float ev[8] = {e0.x, e0.y, e0.z, e0.w, e1.x, e1.y, e1.z, e1.w};
      float rv4[4] = {rv.x, rv.y, rv.z, rv.w};
      #pragma unroll
      for (int i = 0; i < 8; ++i)
        #pragma unroll
        for (int j = 0; j < 4; ++j)
          acc[i][j] = fmaf(ev[i], rv4[j], acc[i][j]);
    }
    // |e| row-sum partials: this thread covers l = dq and dq+16 of the tile
    #pragma unroll
    for (int m = 0; m < 2; ++m) {
      int l = dq + 16 * m;
      float4 a0 = *(const float4*)&et[l * 132 + k0];
      float4 a1 = *(const float4*)&et[l * 132 + k0 + 4];
      s8[0] += fabsf(a0.x); s8[1] += fabsf(a0.y);
      s8[2] += fabsf(a0.z); s8[3] += fabsf(a0.w);
      s8[4] += fabsf(a1.x); s8[5] += fabsf(a1.y);
      s8[6] += fabsf(a1.z); s8[7] += fabsf(a1.w);
    }
    __syncthreads();
  }
  #pragma unroll
  for (int i = 0; i < 8; ++i) atomicAdd(&ssh[k0 + i], s8[i]);
  __syncthreads();
  float* mk = ws + WS_MUK + ((size_t)b * nK + (size_t)kt * 128) * nD;
  #pragma unroll
  for (int i = 0; i < 8; ++i) {
    float inv = 1.f / fmaxf(ssh[k0 + i], 1e-12f);
    float4 o;
    o.x = acc[i][0] * inv; o.y = acc[i][1] * inv;
    o.z = acc[i][2] * inv; o.w = acc[i][3] * inv;
    *(float4*)(mk + (size_t)(k0 + i) * nD + d0) = o;
  }
}

// --------------------------- K4: mean_rl GEMM ------------------------------
// block = (ltile of 128 l, b); reduce over K in chunks of 32 (e transposed).
__global__ __launch_bounds__(256) void k4_mean_rl(
    const float* __restrict__ e, const float* __restrict__ uk,
    float* __restrict__ ws) {
  const int lt = blockIdx.x;   // 0..3
  const int b  = blockIdx.y;
  __shared__ float et[32 * 130];  // [k][l] stride 130 (transposed)
  __shared__ float ut[32 * 68];   // [k][d] stride 68
  __shared__ float tsh[128];
  const int tid = threadIdx.x;
  const int lq = tid >> 4, dq = tid & 15;
  const int l0 = lq * 8, d0 = dq * 4;
  float acc[8][4];
  #pragma unroll
  for (int i = 0; i < 8; ++i)
    #pragma unroll
    for (int j = 0; j < 4; ++j) acc[i][j] = 0.f;
  float t8[8] = {0, 0, 0, 0, 0, 0, 0, 0};
  if (tid < 128) tsh[tid] = 0.f;

  const float* eb = e + ((size_t)b * nL + (size_t)lt * 128) * nK;
  const float* ub = uk + (size_t)b * nK * nD;
  const int ri = tid >> 3;
  const int jseg = (tid & 7) * 4;
  const int dseg = (tid & 7) * 8;

  for (int kc = 0; kc < 16; ++kc) {
    #pragma unroll
    for (int p = 0; p < 4; ++p) {
      int r = ri + 32 * p;
      float4 v = *(const float4*)(eb + (size_t)r * nK + kc * 32 + jseg);
      et[(jseg + 0) * 130 + r] = v.x;
      et[(jseg + 1) * 130 + r] = v.y;
      et[(jseg + 2) * 130 + r] = v.z;
      et[(jseg + 3) * 130 + r] = v.w;
    }
    const float* ur = ub + (size_t)(kc * 32 + ri) * nD;
    #pragma unroll
    for (int q = 0; q < 2; ++q) {
      float4 v = *(const float4*)(ur + dseg + 4 * q);
      *(float4*)&ut[ri * 68 + dseg + 4 * q] = v;
    }
    __syncthreads();
    #pragma unroll 4
    for (int k = 0; k < 32; ++k) {
      float2 e0 = *(const float2*)&et[k * 130 + l0];
      float2 e1 = *(const float2*)&et[k * 130 + l0 + 2];
      float2 e2 = *(const float2*)&et[k * 130 + l0 + 4];
      float2 e3 = *(const float2*)&et[k * 130 + l0 + 6];
      float4 uv = *(const float4*)&ut[k * 68 + d0];
      float ev[8] = {e0.x, e0.y, e1.x, e1.y, e2.x, e2.y, e3.x, e3.y};
      float uv4[4] = {uv.x, uv.y, uv.z, uv.w};
      #pragma unroll
      for (int i = 0; i < 8; ++i)
        #pragma unroll
        for (int j = 0; j < 4; ++j)
          acc[i][j] = fmaf(ev[i], uv4[j], acc[i][j]);
    }
    // |e| row-sum partials: this thread covers k = dq and dq+16 of the chunk
    #pragma unroll
    for (int m = 0; m < 2; ++m) {
      int k = dq + 16 * m;
      #pragma unroll
      for (int i = 0; i < 8; ++i) t8[i] += fabsf(et[k * 130 + l0 + i]);
    }
    __syncthreads();
  }
  #pragma unroll
  for (int i = 0; i < 8; ++i) atomicAdd(&tsh[l0 + i], t8[i]);
  __syncthreads();
  float* mr = ws + WS_MRL + ((size_t)b * nL + (size_t)lt * 128) * nD;
  #pragma unroll
  for (int i = 0; i < 8; ++i) {
    float inv = 1.f / fmaxf(tsh[l0 + i], 1e-12f);
    float4 o;
    o.x = acc[i][0] * inv; o.y = acc[i][1] * inv;
    o.z = acc[i][2] * inv; o.w = acc[i][3] * inv;
    *(float4*)(mr + (size_t)(l0 + i) * nD + d0) = o;
  }
}

// --------------------------- K5: fused node/link MLP -----------------------
// MODE 0: X = [uk | loo_max | mean_uk] (192)  -> uk_update
// MODE 1: X = [rl | mean_rl]           (128)  -> rl_update
// 32 rows/block; hidden 256; out 128 + 64 passthrough.
template <int MODE>
__global__ __launch_bounds__(256) void k_mlp(
    const float* __restrict__ xin, const float* __restrict__ ws,
    const float* __restrict__ w1, const float* __restrict__ b1,
    const float* __restrict__ w2, const float* __restrict__ b2,
    float* __restrict__ out) {
  constexpr int DIN = (MODE == 0) ? 192 : 128;
  constexpr int NCHK = DIN / 32;
  const int kt = blockIdx.x;   // 0..15
  const int b  = blockIdx.y;
  const int row0 = kt * 32;
  __shared__ float buf[12448];   // 49.8 KB, phase-aliased
  float* Xch  = buf;             // [32][33]   (phase 2)
  float* W1ch = buf + 1056;      // [32][260]  (phase 2)
  float* Hs   = buf;             // [32][257]  (phase 3)
  float* W2ch = buf + 8224;      // [32][132]  (phase 3)
  const int tid = threadIdx.x;
  const int hq = tid >> 4, rq = tid & 15;
  const int h0 = hq * 16, r0 = rq * 2;
  float hacc[2][16];
  #pragma unroll
  for (int r = 0; r < 2; ++r)
    #pragma unroll
    for (int q = 0; q < 16; ++q) hacc[r][q] = 0.f;

  const int lr = tid >> 3, lc = (tid & 7) * 4;
  const int wi = tid >> 3, wj = (tid & 7) * 4;
  const size_t xrow = (size_t)b * 512 + row0;

  for (int ch = 0; ch < NCHK; ++ch) {
    // build X chunk
    {
      int g = ch * 32 + lc;
      float4 v;
      if (MODE == 0) {
        if (g < 64) {
          v = *(const float4*)(xin + (xrow + lr) * nD + g);
        } else if (g < 128) {
          int dd = g - 64;
          float4 u  = *(const float4*)(xin + (xrow + lr) * nD + dd);
          float4 m1 = *(const float4*)(ws + WS_MAX1 + (size_t)b * nD + dd);
          float4 m2 = *(const float4*)(ws + WS_MAX2 + (size_t)b * nD + dd);
          v.x = (u.x == m1.x) ? m2.x : m1.x;
          v.y = (u.y == m1.y) ? m2.y : m1.y;
          v.z = (u.z == m1.z) ? m2.z : m1.z;
          v.w = (u.w == m1.w) ? m2.w : m1.w;
        } else {
          v = *(const float4*)(ws + WS_MUK + (xrow + lr) * nD + (g - 128));
        }
      } else {
        if (g < 64) v = *(const float4*)(xin + (xrow + lr) * nD + g);
        else        v = *(const float4*)(ws + WS_MRL + (xrow + lr) * nD + (g - 64));
      }
      Xch[lr * 33 + lc + 0] = v.x;
      Xch[lr * 33 + lc + 1] = v.y;
      Xch[lr * 33 + lc + 2] = v.z;
      Xch[lr * 33 + lc + 3] = v.w;
    }
    // stage W1 chunk [32][256]
    {
      const float* wr = w1 + (size_t)(ch * 32 + wi) * NH;
      #pragma unroll
      for (int q = 0; q < 8; ++q) {
        float4 wv = *(const float4*)(wr + wj + 32 * q);
        *(float4*)&W1ch[wi * 260 + wj + 32 * q] = wv;
      }
    }
    __syncthreads();
    #pragma unroll 2
    for (int ii = 0; ii < 32; ++ii) {
      float x0 = Xch[(r0 + 0) * 33 + ii];
      float x1 = Xch[(r0 + 1) * 33 + ii];
      const float* wl = &W1ch[ii * 260 + h0];
      #pragma unroll
      for (int q = 0; q < 4; ++q) {
        float4 wv = *(const float4*)(wl + 4 * q);
        float wa[4] = {wv.x, wv.y, wv.z, wv.w};
        #pragma unroll
        for (int c = 0; c < 4; ++c) {
          hacc[0][4 * q + c] = fmaf(x0, wa[c], hacc[0][4 * q + c]);
          hacc[1][4 * q + c] = fmaf(x1, wa[c], hacc[1][4 * q + c]);
        }
      }
    }
    __syncthreads();
  }
  // bias + relu -> H (scalar writes; H aliases Xch/W1ch, safe after barrier)
  {
    float bb[16];
    #pragma unroll
    for (int q = 0; q < 4; ++q) {
      float4 t = *(const float4*)(b1 + h0 + 4 * q);
      bb[4 * q + 0] = t.x; bb[4 * q + 1] = t.y;
      bb[4 * q + 2] = t.z; bb[4 * q + 3] = t.w;
    }
    #pragma unroll
    for (int r = 0; r < 2; ++r)
      #pragma unroll
      for (int q = 0; q < 16; ++q)
        Hs[(r0 + r) * 257 + h0 + q] = fmaxf(hacc[r][q] + bb[q], 0.f);
  }
  __syncthreads();
  // phase 3: tmp = H @ W2
  const int cq = tid >> 4;
  const int c0 = cq * 8;
  float acc2[2][8];
  #pragma unroll
  for (int r = 0; r < 2; ++r)
    #pragma unroll
    for (int q = 0; q < 8; ++q) acc2[r][q] = 0.f;
  for (int c2 = 0; c2 < 8; ++c2) {
    const float* w2r = w2 + (size_t)(c2 * 32 + wi) * NC;
    #pragma unroll
    for (int q = 0; q < 4; ++q) {
      float4 wv = *(const float4*)(w2r + wj + 32 * q);
      *(float4*)&W2ch[wi * 132 + wj + 32 * q] = wv;
    }
    __syncthreads();
    #pragma unroll 2
    for (int j = 0; j < 32; ++j) {
      float hx0 = Hs[(r0 + 0) * 257 + c2 * 32 + j];
      float hx1 = Hs[(r0 + 1) * 257 + c2 * 32 + j];
      const float* wl = &W2ch[j * 132 + c0];
      float4 w0v = *(const float4*)(wl);
      float4 w1v = *(const float4*)(wl + 4);
      float wa[8] = {w0v.x, w0v.y, w0v.z, w0v.w, w1v.x, w1v.y, w1v.z, w1v.w};
      #pragma unroll
      for (int c = 0; c < 8; ++c) {
        acc2[0][c] = fmaf(hx0, wa[c], acc2[0][c]);
        acc2[1][c] = fmaf(hx1, wa[c], acc2[1][c]);
      }
    }
    __syncthreads();
  }
  // epilogue: bias + store tmp, then passthrough cols 128..191
  {
    float4 cb0 = *(const float4*)(b2 + c0);
    float4 cb1 = *(const float4*)(b2 + c0 + 4);
    const size_t obase = ((MODE == 0) ? OUT_UK : OUT_RL) + xrow * OC;
    #pragma unroll
    for (int r = 0; r < 2; ++r) {
      float4 o0, o1;
      o0.x = acc2[r][0] + cb0.x; o0.y = acc2[r][1] + cb0.y;
      o0.z = acc2[r][2] + cb0.z; o0.w = acc2[r][3] + cb0.w;
      o1.x = acc2[r][4] + cb1.x; o1.y = acc2[r][5] + cb1.y;
      o1.z = acc2[r][6] + cb1.z; o1.w = acc2[r][7] + cb1.w;
      *(float4*)(out + obase + (size_t)(r0 + r) * OC + c0) = o0;
      *(float4*)(out + obase + (size_t)(r0 + r) * OC + c0 + 4) = o1;
    }
    const int pr = tid >> 3, ps = (tid & 7) * 8;
    const float* xr2 = xin + (xrow + pr) * nD + ps;
    float4 p0 = *(const float4*)(xr2);
    float4 p1 = *(const float4*)(xr2 + 4);
    *(float4*)(out + obase + (size_t)pr * OC + 128 + ps) = p0;
    *(float4*)(out + obase + (size_t)pr * OC + 128 + ps + 4) = p1;
  }
}

// --------------------------- K7: edge scores -------------------------------
// block = (ktile of 64 k, b): scores[b,k] = eu MLP(|uc_up - uk_up[k]|)
__global__ __launch_bounds__(256) void k7_scores(
    const float* __restrict__ outr,
    const float* __restrict__ w1, const float* __restrict__ b1,
    const float* __restrict__ w2, const float* __restrict__ b2,
    float* __restrict__ ws) {
  const int kt = blockIdx.x;   // 0..7
  const int b  = blockIdx.y;
  __shared__ float ucsh[192];
  __shared__ float w2sh[128];
  __shared__ float Xch[64 * 33];
  __shared__ float W1ch[32 * 132];
  __shared__ float red[64 * 17];
  const int tid = threadIdx.x;
  if (tid < 192) ucsh[tid] = outr[OUT_UC + (size_t)b * OC + tid];
  if (tid < 128) w2sh[tid] = w2[tid];
  const int hq = tid >> 4, rq = tid & 15;
  const int h0 = hq * 8, r0 = rq * 4;
  float hacc[4][8];
  #pragma unroll
  for (int i = 0; i < 4; ++i)
    #pragma unroll
    for (int c = 0; c < 8; ++c) hacc[i][c] = 0.f;
  const float* ukup = outr + OUT_UK + ((size_t)b * nK + (size_t)kt * 64) * OC;
  const int xr = tid >> 2, xc = (tid & 3) * 8;
  const int wi = tid >> 3, wj = (tid & 7) * 4;
  __syncthreads();
  for (int ch = 0; ch < 6; ++ch) {
    #pragma unroll
    for (int q = 0; q < 2; ++q) {
      int g = ch * 32 + xc + 4 * q;
      float4 v = *(const float4*)(ukup + (size_t)xr * OC + g);
      Xch[xr * 33 + xc + 4 * q + 0] = fabsf(ucsh[g + 0] - v.x);
      Xch[xr * 33 + xc + 4 * q + 1] = fabsf(ucsh[g + 1] - v.y);
      Xch[xr * 33 + xc + 4 * q + 2] = fabsf(ucsh[g + 2] - v.z);
      Xch[xr * 33 + xc + 4 * q + 3] = fabsf(ucsh[g + 3] - v.w);
    }
    #pragma unroll
    for (int q = 0; q < 4; ++q) {
      float4 wv = *(const float4*)(w1 + (size_t)(ch * 32 + wi) * NC + wj + 32 * q);
      *(float4*)&W1ch[wi * 132 + wj + 32 * q] = wv;
    }
    __syncthreads();
    #pragma unroll 2
    for (int ii = 0; ii < 32; ++ii) {
      float xv[4];
      #pragma unroll
      for (int i = 0; i < 4; ++i) xv[i] = Xch[(r0 + i) * 33 + ii];
      float4 w0v = *(const float4*)&W1ch[ii * 132 + h0];
      float4 w1v = *(const float4*)&W1ch[ii * 132 + h0 + 4];
      float wa[8] = {w0v.x, w0v.y, w0v.z, w0v.w, w1v.x, w1v.y, w1v.z, w1v.w};
      #pragma unroll
      for (int i = 0; i < 4; ++i)
        #pragma unroll
        for (int c = 0; c < 8; ++c)
          hacc[i][c] = fmaf(xv[i], wa[c], hacc[i][c]);
    }
    __syncthreads();
  }
  {
    float4 ba = *(const float4*)(b1 + h0);
    float4 bbv = *(const float4*)(b1 + h0 + 4);
    float bv[8] = {ba.x, ba.y, ba.z, ba.w, bbv.x, bbv.y, bbv.z, bbv.w};
    #pragma unroll
    for (int i = 0; i < 4; ++i) {
      float p = 0.f;
      #pragma unroll
      for (int c = 0; c < 8; ++c) {
        float h = fmaxf(hacc[i][c] + bv[c], 0.f);
        p = fmaf(h, w2sh[h0 + c], p);
      }
      red[(r0 + i) * 17 + hq] = p;
    }
  }
  __syncthreads();
  if (tid < 64) {
    float s = b2[0];
    #pragma unroll
    for (int q = 0; q < 16; ++q) s += red[tid * 17 + q];
    ws[WS_SC + (size_t)b * nK + (size_t)kt * 64 + tid] = s;
  }
}

// --------------------------- K8: softmax over K ----------------------------
__global__ __launch_bounds__(256) void k8_softmax(
    const float* __restrict__ ws, float* __restrict__ out) {
  const int b = blockIdx.x;
  const int t = threadIdx.x;
  const float* s = ws + WS_SC + (size_t)b * nK;
  float v0 = s[t], v1 = s[t + 256];
  float m = fmaxf(v0, v1);
  #pragma unroll
  for (int off = 32; off; off >>= 1) m = fmaxf(m, __shfl_xor(m, off));
  __shared__ float sm[4], ssum[4];
  const int w = t >> 6;
  if ((t & 63) == 0) sm[w] = m;
  __syncthreads();
  m = fmaxf(fmaxf(sm[0], sm[1]), fmaxf(sm[2], sm[3]));
  float e0 = expf(v0 - m), e1 = expf(v1 - m);
  float sum = e0 + e1;
  #pragma unroll
  for (int off = 32; off; off >>= 1) sum += __shfl_xor(sum, off);
  if ((t & 63) == 0) ssum[w] = sum;
  __syncthreads();
  float inv = 1.f / (ssum[0] + ssum[1] + ssum[2] + ssum[3]);
  out[OUT_ERC + (size_t)b * nK + t] = e0 * inv;
  out[OUT_ERC + (size_t)b * nK + t + 256] = e1 * inv;
}

// --------------------------- launch ----------------------------------------
extern "C" void kernel_launch(void* const* d_in, const int* in_sizes, int n_in,
                              void* d_out, int out_size, void* d_ws,
                              size_t ws_size, hipStream_t stream) {
  (void)in_sizes; (void)n_in; (void)out_size; (void)ws_size;
  const float* uk    = (const float*)d_in[0];
  const float* uc    = (const float*)d_in[1];
  const float* rl    = (const float*)d_in[2];
  const float* e     = (const float*)d_in[3];
  const float* e_rc  = (const float*)d_in[4];
  const float* fu_w1 = (const float*)d_in[5];
  const float* fu_b1 = (const float*)d_in[6];
  const float* fu_w2 = (const float*)d_in[7];
  const float* fu_b2 = (const float*)d_in[8];
  const float* f_w1  = (const float*)d_in[9];
  const float* f_b1  = (const float*)d_in[10];
  const float* f_w2  = (const float*)d_in[11];
  const float* f_b2  = (const float*)d_in[12];
  const float* fc_w1 = (const float*)d_in[13];
  const float* fc_b1 = (const float*)d_in[14];
  const float* fc_w2 = (const float*)d_in[15];
  const float* fc_b2 = (const float*)d_in[16];
  const float* eu_w1 = (const float*)d_in[17];
  const float* eu_b1 = (const float*)d_in[18];
  const float* eu_w2 = (const float*)d_in[19];
  const float* eu_b2 = (const float*)d_in[20];
  float* out = (float*)d_out;
  float* ws  = (float*)d_ws;

  k1_topk_meanuc<<<nB, 256, 0, stream>>>(uk, e_rc, ws);
  k3_mean_uk<<<dim3(4, nB), 256, 0, stream>>>(e, rl, ws);
  k4_mean_rl<<<dim3(4, nB), 256, 0, stream>>>(e, uk, ws);
  k2_uc_mlp<<<nB, 256, 0, stream>>>(uc, ws, fc_w1, fc_b1, fc_w2, fc_b2, out);
  k_mlp<0><<<dim3(16, nB), 256, 0, stream>>>(uk, ws, fu_w1, fu_b1, fu_w2, fu_b2, out);
  k_mlp<1><<<dim3(16, nB), 256, 0, stream>>>(rl, ws, f_w1, f_b1, f_w2, f_b2, out);
  k7_scores<<<dim3(8, nB), 256, 0, stream>>>(out, eu_w1, eu_b1, eu_w2, eu_b2, ws);
  k8_softmax<<<nB, 256, 0, stream>>>(ws, out);
}